// Round 1
// baseline (813.447 us; speedup 1.0000x reference)
//
#include <hip/hip_runtime.h>

// Simple_TensorProduct: (256x0e + 256x1o) x (1x0e + 1x1o) -> 256x0e + 256x1o
// uvu weights, 5 paths. Memory-bound elementwise-per-(z,u) kernel.
//
// Per z, per u:
//   o0[u]   = C0*( w0[u]*x0[u]*y0 + S3*w1[u]*dot(x1[u], y1) )
//   o1[u,k] = S3*w2[u]*x0[u]*y1[k] + S3*w3[u]*y0*x1[u,k] + C6*w4[u]*cross(x1[u],y1)[k]
// with C0 = sqrt(1/2), S3 = 1/sqrt(3), C6 = 1/sqrt(6).

namespace {

constexpr int MUL = 256;
constexpr int ROW = MUL * 4;  // 1024 floats per row (x and out)

struct f3 { float x, y, z; };  // 12B, align 4 -> global_load_dwordx3

__global__ __launch_bounds__(256) void tp_kernel(
    const float* __restrict__ x,
    const float* __restrict__ y,
    const float* __restrict__ w,
    float* __restrict__ out)
{
    const int z = blockIdx.x;      // one block per batch row
    const int u = threadIdx.x;     // one thread per channel

    // y row: 4 floats, broadcast across the block (single cached load)
    const float4 yv = reinterpret_cast<const float4*>(y)[z];
    const float y0  = yv.x;
    const float y1x = yv.y, y1y = yv.z, y1z = yv.w;

    const float* xp = x   + (size_t)z * ROW;
    float*       op = out + (size_t)z * ROW;

    // coalesced: dword for x0, dwordx3 for x1 (768 contiguous floats per row)
    const float x0 = xp[u];
    const f3 x1 = reinterpret_cast<const f3*>(xp + MUL)[u];

    // weights: 5*256 floats total, L1-resident after first block; coalesced
    const float w0 = w[u];
    const float w1 = w[MUL + u];
    const float w2 = w[2 * MUL + u];
    const float w3 = w[3 * MUL + u];
    const float w4 = w[4 * MUL + u];

    constexpr float C0 = 0.70710678118654752f;  // sqrt(1/2)
    constexpr float S3 = 0.57735026918962576f;  // 1/sqrt(3)
    constexpr float C6 = 0.40824829046386302f;  // 1/sqrt(6)

    const float dot = x1.x * y1x + x1.y * y1y + x1.z * y1z;
    const float cx  = x1.y * y1z - x1.z * y1y;
    const float cy  = x1.z * y1x - x1.x * y1z;
    const float cz  = x1.x * y1y - x1.y * y1x;

    // 0e output
    op[u] = C0 * (w0 * x0 * y0 + S3 * w1 * dot);

    // 1o output
    const float a = S3 * w2 * x0;   // * y1[k]
    const float b = S3 * w3 * y0;   // * x1[k]
    const float c = C6 * w4;        // * cross[k]
    f3 o1;
    o1.x = a * y1x + b * x1.x + c * cx;
    o1.y = a * y1y + b * x1.y + c * cy;
    o1.z = a * y1z + b * x1.z + c * cz;
    reinterpret_cast<f3*>(op + MUL)[u] = o1;
}

}  // namespace

extern "C" void kernel_launch(void* const* d_in, const int* in_sizes, int n_in,
                              void* d_out, int out_size, void* d_ws, size_t ws_size,
                              hipStream_t stream) {
    const float* x = (const float*)d_in[0];   // (B, 1024)
    const float* y = (const float*)d_in[1];   // (B, 4)
    const float* w = (const float*)d_in[2];   // (1280,)
    float* out = (float*)d_out;               // (B, 1024)

    const int B = in_sizes[0] / ROW;          // 131072
    tp_kernel<<<B, MUL, 0, stream>>>(x, y, w, out);
}